// Round 6
// baseline (278.694 us; speedup 1.0000x reference)
//
#include <hip/hip_runtime.h>

static constexpr int NN = 50000;   // nodes
static constexpr int NE = 800000;  // edges
static constexpr int D0 = 128;     // in dim
static constexpr int D1 = 256;     // hidden
static constexpr int D2 = 5;       // out
static constexpr int NB = (NN + 255) / 256;  // 196 scan blocks

// fused prep grid partition
static constexpr int HB = (NE + 255) / 256;        // 3125 hist blocks
static constexpr int XB = (NN * 32 + 255) / 256;   // 6250 cvtx blocks
static constexpr int WB = (D1 * 64) / 256;         // 64 cvtw blocks

using short8  = __attribute__((ext_vector_type(8))) short;
using floatx4 = __attribute__((ext_vector_type(4))) float;

__device__ __forceinline__ unsigned short f2b(float f) {
  union { float f; unsigned u; } v; v.f = f;
  unsigned r = v.u + 0x7fffu + ((v.u >> 16) & 1u);  // RNE
  return (unsigned short)(r >> 16);
}
__device__ __forceinline__ float b2f(unsigned short s) {
  union { unsigned u; float f; } v; v.u = ((unsigned)s) << 16;
  return v.f;
}

// ------------------------------------------------- fused prep: hist|cvtx|cvtw
__global__ __launch_bounds__(256) void k_prep(
    const int* __restrict__ dst, int* __restrict__ deg,
    const float* __restrict__ x, unsigned short* __restrict__ ab,
    const float* __restrict__ W1l, const float* __restrict__ W1r,
    unsigned short* __restrict__ wb) {
  const int b = blockIdx.x, t = threadIdx.x;
  if (b < HB) {  // histogram of dst
    int e = b * 256 + t;
    if (e < NE) atomicAdd(&deg[dst[e]], 1);
  } else if (b < HB + XB) {  // x -> bf16 into ab cols 128..255
    int idx = (b - HB) * 256 + t;
    if (idx < NN * 32) {
      int node = idx >> 5, cg = idx & 31;
      float4 v = *(const float4*)(x + (size_t)node * D0 + cg * 4);
      ushort4 o;
      o.x = f2b(v.x); o.y = f2b(v.y); o.z = f2b(v.z); o.w = f2b(v.w);
      *(ushort4*)(ab + (size_t)node * 256 + 128 + cg * 4) = o;
    }
  } else {  // [W1l|W1r] -> bf16 wb[col][256]
    int idx = (b - HB - XB) * 256 + t;
    int c = idx >> 6, k = (idx & 63) * 4;
    const float* srcp = (k < 128) ? (W1l + (size_t)c * 128 + k)
                                  : (W1r + (size_t)c * 128 + (k - 128));
    float4 v = *(const float4*)srcp;
    ushort4 o;
    o.x = f2b(v.x); o.y = f2b(v.y); o.z = f2b(v.z); o.w = f2b(v.w);
    *(ushort4*)(wb + (size_t)c * 256 + k) = o;
  }
}

// ---------------------------------------------------------------- scan
__global__ __launch_bounds__(256) void k_scanA(const int* __restrict__ deg,
                                               int* __restrict__ cur,
                                               int* __restrict__ bsum) {
  __shared__ int s[256];
  const int t = threadIdx.x;
  const int i = blockIdx.x * 256 + t;
  const int v = (i < NN) ? deg[i] : 0;
  s[t] = v;
  __syncthreads();
  for (int d = 1; d < 256; d <<= 1) {
    int u = (t >= d) ? s[t - d] : 0;
    __syncthreads();
    s[t] += u;
    __syncthreads();
  }
  if (i < NN) cur[i] = s[t] - v;
  if (t == 255) bsum[blockIdx.x] = s[255];
}

__global__ __launch_bounds__(256) void k_scanB(const int* __restrict__ deg,
                                               const int* __restrict__ bsum,
                                               int* __restrict__ cur,
                                               float* __restrict__ inv) {
  __shared__ int s[256];
  const int t = threadIdx.x;
  s[t] = (t < NB) ? bsum[t] : 0;
  __syncthreads();
  for (int d = 1; d < 256; d <<= 1) {
    int u = (t >= d) ? s[t - d] : 0;
    __syncthreads();
    s[t] += u;
    __syncthreads();
  }
  const int boff = (blockIdx.x == 0) ? 0 : s[blockIdx.x - 1];
  const int i = blockIdx.x * 256 + t;
  if (i < NN) {
    cur[i] += boff;
    inv[i] = 1.0f / (float)max(deg[i], 1);
  }
}

__global__ __launch_bounds__(256) void k_sortedges(const int* __restrict__ src,
                                                   const int* __restrict__ dst,
                                                   int* __restrict__ cur,
                                                   int* __restrict__ esort) {
  int e = blockIdx.x * blockDim.x + threadIdx.x;
  if (e < NE) {
    int p = atomicAdd(&cur[dst[e]], 1);
    esort[p] = src[e];
  }
}

// ---------------------------------------------------------------- aggregate 1
// one wave per node; lane covers 2 bf16 cols. int4 index loads, 8 gathers in flight.
__global__ __launch_bounds__(256) void k_agg1(
    unsigned short* __restrict__ ab, const int* __restrict__ esort,
    const int* __restrict__ cur, const float* __restrict__ inv) {
  const int i = (blockIdx.x * 256 + threadIdx.x) >> 6;
  const int lane = threadIdx.x & 63;
  if (i >= NN) return;
  int e = (i == 0) ? 0 : cur[i - 1];
  const int end = cur[i];
  float a0 = 0.f, b0 = 0.f, a1 = 0.f, b1 = 0.f;
  float a2 = 0.f, b2 = 0.f, a3 = 0.f, b3 = 0.f;
  const unsigned short* xb = ab + 128 + lane * 2;
  // align e to 4 for int4 index loads
  while (e < end && (e & 3)) {
    const unsigned v = *(const unsigned*)(xb + (size_t)esort[e] * 256);
    a0 += b2f((unsigned short)v); b0 += b2f((unsigned short)(v >> 16));
    ++e;
  }
  for (; e + 7 < end; e += 8) {
    const int4 s0 = *(const int4*)(esort + e);
    const int4 s1 = *(const int4*)(esort + e + 4);
    const unsigned v0 = *(const unsigned*)(xb + (size_t)s0.x * 256);
    const unsigned v1 = *(const unsigned*)(xb + (size_t)s0.y * 256);
    const unsigned v2 = *(const unsigned*)(xb + (size_t)s0.z * 256);
    const unsigned v3 = *(const unsigned*)(xb + (size_t)s0.w * 256);
    const unsigned v4 = *(const unsigned*)(xb + (size_t)s1.x * 256);
    const unsigned v5 = *(const unsigned*)(xb + (size_t)s1.y * 256);
    const unsigned v6 = *(const unsigned*)(xb + (size_t)s1.z * 256);
    const unsigned v7 = *(const unsigned*)(xb + (size_t)s1.w * 256);
    a0 += b2f((unsigned short)v0); b0 += b2f((unsigned short)(v0 >> 16));
    a1 += b2f((unsigned short)v1); b1 += b2f((unsigned short)(v1 >> 16));
    a2 += b2f((unsigned short)v2); b2 += b2f((unsigned short)(v2 >> 16));
    a3 += b2f((unsigned short)v3); b3 += b2f((unsigned short)(v3 >> 16));
    a0 += b2f((unsigned short)v4); b0 += b2f((unsigned short)(v4 >> 16));
    a1 += b2f((unsigned short)v5); b1 += b2f((unsigned short)(v5 >> 16));
    a2 += b2f((unsigned short)v6); b2 += b2f((unsigned short)(v6 >> 16));
    a3 += b2f((unsigned short)v7); b3 += b2f((unsigned short)(v7 >> 16));
  }
  if (e + 3 < end) {
    const int4 s0 = *(const int4*)(esort + e);
    const unsigned v0 = *(const unsigned*)(xb + (size_t)s0.x * 256);
    const unsigned v1 = *(const unsigned*)(xb + (size_t)s0.y * 256);
    const unsigned v2 = *(const unsigned*)(xb + (size_t)s0.z * 256);
    const unsigned v3 = *(const unsigned*)(xb + (size_t)s0.w * 256);
    a0 += b2f((unsigned short)v0); b0 += b2f((unsigned short)(v0 >> 16));
    a1 += b2f((unsigned short)v1); b1 += b2f((unsigned short)(v1 >> 16));
    a2 += b2f((unsigned short)v2); b2 += b2f((unsigned short)(v2 >> 16));
    a3 += b2f((unsigned short)v3); b3 += b2f((unsigned short)(v3 >> 16));
    e += 4;
  }
  for (; e < end; ++e) {
    const unsigned v = *(const unsigned*)(xb + (size_t)esort[e] * 256);
    a0 += b2f((unsigned short)v); b0 += b2f((unsigned short)(v >> 16));
  }
  const float sc = inv[i];
  const float sa = (a0 + a1) + (a2 + a3);
  const float sb = (b0 + b1) + (b2 + b3);
  const unsigned out =
      ((unsigned)f2b(sb * sc) << 16) | (unsigned)f2b(sa * sc);
  *(unsigned*)(ab + (size_t)i * 256 + lane * 2) = out;
}

// ---------------------------------------------------------------- GEMM 1 (MFMA)
// hb = relu( ab[50000,256] @ wb[256,256]^T + b1l ), 128x128 tile, 4 waves 2x2,
// each wave 4x4 16x16x32 mfma tiles.
__global__ __launch_bounds__(256) void k_gemm1(
    const unsigned short* __restrict__ ab, const unsigned short* __restrict__ wb,
    const float* __restrict__ b1l, unsigned short* __restrict__ hb) {
  __shared__ short sA[128 * 40];  // [row][k], stride 40 shorts
  __shared__ short sB[128 * 40];  // [col][k]
  const int tid = threadIdx.x;
  const int row0 = blockIdx.y * 128;
  const int col0 = blockIdx.x * 128;
  const int wave = tid >> 6, lane = tid & 63;
  const int quad = lane >> 4, m16 = lane & 15;
  const int wm = wave & 1, wn = wave >> 1;
  const int lr = tid >> 2;       // 0..63
  const int lk = (tid & 3) * 8;  // 0,8,16,24

  floatx4 acc[4][4];
#pragma unroll
  for (int a = 0; a < 4; ++a)
#pragma unroll
    for (int b = 0; b < 4; ++b) acc[a][b] = {0.f, 0.f, 0.f, 0.f};

  const int gr0 = row0 + lr, gr1 = row0 + lr + 64;
  const bool ok0 = gr0 < NN, ok1 = gr1 < NN;
  const unsigned short* aptr0 = ab + (size_t)gr0 * 256 + lk;
  const unsigned short* aptr1 = ab + (size_t)gr1 * 256 + lk;
  const unsigned short* bptr0 = wb + (size_t)(col0 + lr) * 256 + lk;
  const unsigned short* bptr1 = wb + (size_t)(col0 + lr + 64) * 256 + lk;
  short* sA0 = &sA[lr * 40 + lk];
  short* sA1 = &sA[(lr + 64) * 40 + lk];
  short* sB0 = &sB[lr * 40 + lk];
  short* sB1 = &sB[(lr + 64) * 40 + lk];
  const uint4 zz = make_uint4(0, 0, 0, 0);

  for (int kk = 0; kk < 256; kk += 32) {
    const uint4 av0 = ok0 ? *(const uint4*)(aptr0 + kk) : zz;
    const uint4 av1 = ok1 ? *(const uint4*)(aptr1 + kk) : zz;
    const uint4 bv0 = *(const uint4*)(bptr0 + kk);
    const uint4 bv1 = *(const uint4*)(bptr1 + kk);
    __syncthreads();
    *(uint4*)sA0 = av0;
    *(uint4*)sA1 = av1;
    *(uint4*)sB0 = bv0;
    *(uint4*)sB1 = bv1;
    __syncthreads();
    short8 af[4], bf[4];
#pragma unroll
    for (int mt = 0; mt < 4; ++mt)
      af[mt] = *(const short8*)&sA[(wm * 64 + mt * 16 + m16) * 40 + quad * 8];
#pragma unroll
    for (int nt = 0; nt < 4; ++nt)
      bf[nt] = *(const short8*)&sB[(wn * 64 + nt * 16 + m16) * 40 + quad * 8];
#pragma unroll
    for (int mt = 0; mt < 4; ++mt)
#pragma unroll
      for (int nt = 0; nt < 4; ++nt)
        acc[mt][nt] = __builtin_amdgcn_mfma_f32_16x16x32_bf16(
            af[mt], bf[nt], acc[mt][nt], 0, 0, 0);
  }

#pragma unroll
  for (int nt = 0; nt < 4; ++nt) {
    const int col = col0 + wn * 64 + nt * 16 + m16;
    const float bias = b1l[col];
#pragma unroll
    for (int mt = 0; mt < 4; ++mt) {
#pragma unroll
      for (int rg = 0; rg < 4; ++rg) {
        const int row = row0 + wm * 64 + mt * 16 + quad * 4 + rg;
        if (row < NN)
          hb[(size_t)row * 256 + col] = f2b(fmaxf(acc[mt][nt][rg] + bias, 0.f));
      }
    }
  }
}

// ---------------------------------------------------------------- layer-2 lin
// t rows padded to stride 8 (cols 5..7 unused) for vector gathers in k_layer2.
__global__ __launch_bounds__(256) void k_lin2(
    const unsigned short* __restrict__ hb, const float* __restrict__ W2l,
    const float* __restrict__ W2r, float* __restrict__ t,
    float* __restrict__ r) {
  __shared__ float sW[2 * D2 * D1];
  for (int idx = threadIdx.x; idx < 2 * D2 * D1; idx += 256)
    sW[idx] = (idx < D2 * D1) ? W2l[idx] : W2r[idx - D2 * D1];
  __syncthreads();
  const int i = blockIdx.x * 256 + threadIdx.x;
  if (i >= NN) return;
  float accl[5] = {}, accr[5] = {};
  const unsigned short* hr = hb + (size_t)i * D1;
  for (int k = 0; k < D1; k += 8) {
    const uint4 hv = *(const uint4*)(hr + k);
    float hf[8];
    hf[0] = b2f((unsigned short)hv.x); hf[1] = b2f((unsigned short)(hv.x >> 16));
    hf[2] = b2f((unsigned short)hv.y); hf[3] = b2f((unsigned short)(hv.y >> 16));
    hf[4] = b2f((unsigned short)hv.z); hf[5] = b2f((unsigned short)(hv.z >> 16));
    hf[6] = b2f((unsigned short)hv.w); hf[7] = b2f((unsigned short)(hv.w >> 16));
#pragma unroll
    for (int n = 0; n < 5; ++n) {
      const float* wl = &sW[n * D1 + k];
      const float* wr = &sW[D2 * D1 + n * D1 + k];
#pragma unroll
      for (int j = 0; j < 8; ++j) {
        accl[n] += hf[j] * wl[j];
        accr[n] += hf[j] * wr[j];
      }
    }
  }
#pragma unroll
  for (int n = 0; n < 5; ++n) {
    t[(size_t)i * 8 + n] = accl[n];
    r[(size_t)i * D2 + n] = accr[n];
  }
}

// ---------------------------------------------------------------- layer-2 agg
__global__ __launch_bounds__(256) void k_layer2(
    const float* __restrict__ t, const float* __restrict__ r,
    const int* __restrict__ esort, const int* __restrict__ cur,
    const float* __restrict__ inv, const float* __restrict__ b2l,
    float* __restrict__ out) {
  const int i = blockIdx.x * blockDim.x + threadIdx.x;
  if (i >= NN) return;
  float A0 = 0, A1 = 0, A2 = 0, A3 = 0, A4 = 0;
  float B0 = 0, B1 = 0, B2 = 0, B3 = 0, B4 = 0;
  int e = (i == 0) ? 0 : cur[i - 1];
  const int end = cur[i];
  while (e < end && (e & 3)) {
    const float* tp = t + (size_t)esort[e] * 8;
    const float4 p = *(const float4*)tp;
    A0 += p.x; A1 += p.y; A2 += p.z; A3 += p.w; A4 += tp[4];
    ++e;
  }
  for (; e + 3 < end; e += 4) {
    const int4 s = *(const int4*)(esort + e);
    const float* t0 = t + (size_t)s.x * 8;
    const float* t1 = t + (size_t)s.y * 8;
    const float* t2 = t + (size_t)s.z * 8;
    const float* t3 = t + (size_t)s.w * 8;
    const float4 p0 = *(const float4*)t0; const float q0 = t0[4];
    const float4 p1 = *(const float4*)t1; const float q1 = t1[4];
    const float4 p2 = *(const float4*)t2; const float q2 = t2[4];
    const float4 p3 = *(const float4*)t3; const float q3 = t3[4];
    A0 += p0.x; A1 += p0.y; A2 += p0.z; A3 += p0.w; A4 += q0;
    B0 += p1.x; B1 += p1.y; B2 += p1.z; B3 += p1.w; B4 += q1;
    A0 += p2.x; A1 += p2.y; A2 += p2.z; A3 += p2.w; A4 += q2;
    B0 += p3.x; B1 += p3.y; B2 += p3.z; B3 += p3.w; B4 += q3;
  }
  for (; e < end; ++e) {
    const float* tp = t + (size_t)esort[e] * 8;
    const float4 p = *(const float4*)tp;
    A0 += p.x; A1 += p.y; A2 += p.z; A3 += p.w; A4 += tp[4];
  }
  const float sc = inv[i];
  const float* rp = r + (size_t)i * D2;
  out[(size_t)i * D2 + 0] = fmaxf((A0 + B0) * sc + b2l[0] + rp[0], 0.f);
  out[(size_t)i * D2 + 1] = fmaxf((A1 + B1) * sc + b2l[1] + rp[1], 0.f);
  out[(size_t)i * D2 + 2] = fmaxf((A2 + B2) * sc + b2l[2] + rp[2], 0.f);
  out[(size_t)i * D2 + 3] = fmaxf((A3 + B3) * sc + b2l[3] + rp[3], 0.f);
  out[(size_t)i * D2 + 4] = fmaxf((A4 + B4) * sc + b2l[4] + rp[4], 0.f);
}

extern "C" void kernel_launch(void* const* d_in, const int* in_sizes, int n_in,
                              void* d_out, int out_size, void* d_ws,
                              size_t ws_size, hipStream_t stream) {
  const float* x   = (const float*)d_in[0];
  const int*   ei  = (const int*)d_in[1];
  const int*   src = ei;
  const int*   dst = ei + NE;
  const float* W1l = (const float*)d_in[2];
  const float* b1l = (const float*)d_in[3];
  const float* W1r = (const float*)d_in[4];
  const float* W2l = (const float*)d_in[5];
  const float* b2l = (const float*)d_in[6];
  const float* W2r = (const float*)d_in[7];
  float* out = (float*)d_out;

  // workspace layout (4-byte units)
  int*   deg   = (int*)d_ws;                     // NN
  int*   cur   = deg + NN;                       // NN
  int*   bsum  = cur + NN;                       // 256
  int*   esort = bsum + 256;                     // NE
  float* inv   = (float*)(esort + NE);           // NN
  unsigned short* ab = (unsigned short*)(inv + NN);        // NN*256 bf16
  unsigned short* wb = ab + (size_t)NN * 256;              // 256*256 bf16
  unsigned short* hb = wb + (size_t)D1 * 256;              // NN*256 bf16
  float* t = (float*)(hb + (size_t)NN * 256);              // NN*8 (padded)
  float* r = t + (size_t)NN * 8;                           // NN*5

  hipMemsetAsync(deg, 0, (size_t)NN * sizeof(int), stream);

  k_prep<<<HB + XB + WB, 256, 0, stream>>>(dst, deg, x, ab, W1l, W1r, wb);
  k_scanA<<<NB, 256, 0, stream>>>(deg, cur, bsum);
  k_scanB<<<NB, 256, 0, stream>>>(deg, bsum, cur, inv);
  k_sortedges<<<(NE + 255) / 256, 256, 0, stream>>>(src, dst, cur, esort);
  k_agg1<<<(NN * 64 + 255) / 256, 256, 0, stream>>>(ab, esort, cur, inv);
  dim3 g1(2, (NN + 127) / 128);
  k_gemm1<<<g1, 256, 0, stream>>>(ab, wb, b1l, hb);
  k_lin2<<<(NN + 255) / 256, 256, 0, stream>>>(hb, W2l, W2r, t, r);
  k_layer2<<<(NN + 255) / 256, 256, 0, stream>>>(t, r, esort, cur, inv, b2l, out);
}

// Round 7
// 267.510 us; speedup vs baseline: 1.0418x; 1.0418x over previous
//
#include <hip/hip_runtime.h>

static constexpr int NN = 50000;   // nodes
static constexpr int NE = 800000;  // edges
static constexpr int D0 = 128;     // in dim
static constexpr int D1 = 256;     // hidden
static constexpr int D2 = 5;       // out
static constexpr int NB = (NN + 255) / 256;  // 196 scan blocks

// fused prep grid partition
static constexpr int HB = (NE + 255) / 256;        // 3125 hist blocks
static constexpr int XB = (NN * 32 + 255) / 256;   // 6250 cvtx blocks
static constexpr int WB = (D1 * 64) / 256;         // 64 cvtw blocks

// bucketed edge sort
static constexpr int NBUK  = 100;    // dst-range buckets
static constexpr int BSZ   = 500;    // nodes per bucket
static constexpr int CAP   = 12288;  // slab capacity per bucket (mean 8000, sd 89)
static constexpr int CB    = 400;    // chunk blocks in pass A
static constexpr int CHUNK = 2000;   // edges per chunk (CB*CHUNK == NE)

using short8  = __attribute__((ext_vector_type(8))) short;
using floatx4 = __attribute__((ext_vector_type(4))) float;

__device__ __forceinline__ unsigned short f2b(float f) {
  union { float f; unsigned u; } v; v.f = f;
  unsigned r = v.u + 0x7fffu + ((v.u >> 16) & 1u);  // RNE
  return (unsigned short)(r >> 16);
}
__device__ __forceinline__ float b2f(unsigned short s) {
  union { unsigned u; float f; } v; v.u = ((unsigned)s) << 16;
  return v.f;
}

// ------------------------------------------------- fused prep: hist|cvtx|cvtw
__global__ __launch_bounds__(256) void k_prep(
    const int* __restrict__ dst, int* __restrict__ deg,
    const float* __restrict__ x, unsigned short* __restrict__ ab,
    const float* __restrict__ W1l, const float* __restrict__ W1r,
    unsigned short* __restrict__ wb) {
  const int b = blockIdx.x, t = threadIdx.x;
  if (b < HB) {  // histogram of dst
    int e = b * 256 + t;
    if (e < NE) atomicAdd(&deg[dst[e]], 1);
  } else if (b < HB + XB) {  // x -> bf16 into ab cols 128..255
    int idx = (b - HB) * 256 + t;
    if (idx < NN * 32) {
      int node = idx >> 5, cg = idx & 31;
      float4 v = *(const float4*)(x + (size_t)node * D0 + cg * 4);
      ushort4 o;
      o.x = f2b(v.x); o.y = f2b(v.y); o.z = f2b(v.z); o.w = f2b(v.w);
      *(ushort4*)(ab + (size_t)node * 256 + 128 + cg * 4) = o;
    }
  } else {  // [W1l|W1r] -> bf16 wb[col][256]
    int idx = (b - HB - XB) * 256 + t;
    int c = idx >> 6, k = (idx & 63) * 4;
    const float* srcp = (k < 128) ? (W1l + (size_t)c * 128 + k)
                                  : (W1r + (size_t)c * 128 + (k - 128));
    float4 v = *(const float4*)srcp;
    ushort4 o;
    o.x = f2b(v.x); o.y = f2b(v.y); o.z = f2b(v.z); o.w = f2b(v.w);
    *(ushort4*)(wb + (size_t)c * 256 + k) = o;
  }
}

// ---------------------------------------------------------------- scan
__global__ __launch_bounds__(256) void k_scanA(const int* __restrict__ deg,
                                               int* __restrict__ cur,
                                               int* __restrict__ bsum) {
  __shared__ int s[256];
  const int t = threadIdx.x;
  const int i = blockIdx.x * 256 + t;
  const int v = (i < NN) ? deg[i] : 0;
  s[t] = v;
  __syncthreads();
  for (int d = 1; d < 256; d <<= 1) {
    int u = (t >= d) ? s[t - d] : 0;
    __syncthreads();
    s[t] += u;
    __syncthreads();
  }
  if (i < NN) cur[i] = s[t] - v;
  if (t == 255) bsum[blockIdx.x] = s[255];
}

// cur stays as START offsets; sentinel cur[NN]=NE added here.
__global__ __launch_bounds__(256) void k_scanB(const int* __restrict__ deg,
                                               const int* __restrict__ bsum,
                                               int* __restrict__ cur,
                                               float* __restrict__ inv) {
  __shared__ int s[256];
  const int t = threadIdx.x;
  s[t] = (t < NB) ? bsum[t] : 0;
  __syncthreads();
  for (int d = 1; d < 256; d <<= 1) {
    int u = (t >= d) ? s[t - d] : 0;
    __syncthreads();
    s[t] += u;
    __syncthreads();
  }
  const int boff = (blockIdx.x == 0) ? 0 : s[blockIdx.x - 1];
  const int i = blockIdx.x * 256 + t;
  if (i < NN) {
    cur[i] += boff;
    inv[i] = 1.0f / (float)max(deg[i], 1);
  }
  if (blockIdx.x == 0 && t == 0) cur[NN] = NE;
}

// -------------------------------------------- bucketed edge sort, pass A
// chunk -> LDS bucket-sort -> coalesced slab writes (per-bucket reservation)
__global__ __launch_bounds__(256) void k_bucketA(
    const int* __restrict__ src, const int* __restrict__ dst,
    int* __restrict__ gcur, uint2* __restrict__ slab) {
  __shared__ int hist[128], bstart[128], gbase[128], hcur[128], sscan[128];
  __shared__ uint2 pairs[CHUNK];
  const int t = threadIdx.x;
  const int e0 = blockIdx.x * CHUNK;
  if (t < 128) hist[t] = 0;
  __syncthreads();
  for (int j = t; j < CHUNK; j += 256)
    atomicAdd(&hist[dst[e0 + j] / BSZ], 1);
  __syncthreads();
  if (t < 128) sscan[t] = hist[t];
  __syncthreads();
  for (int dd = 1; dd < 128; dd <<= 1) {
    int u = (t >= dd && t < 128) ? sscan[t - dd] : 0;
    __syncthreads();
    if (t < 128) sscan[t] += u;
    __syncthreads();
  }
  if (t < 128) {
    bstart[t] = sscan[t] - hist[t];
    gbase[t] = (t < NBUK && hist[t] > 0) ? atomicAdd(&gcur[t], hist[t]) : 0;
    hcur[t] = 0;
  }
  __syncthreads();
  for (int j = t; j < CHUNK; j += 256) {
    const int s = src[e0 + j], d = dst[e0 + j];
    const int b = d / BSZ;
    const int pos = bstart[b] + atomicAdd(&hcur[b], 1);
    pairs[pos] = make_uint2((unsigned)s, (unsigned)d);
  }
  __syncthreads();
  for (int j = t; j < CHUNK; j += 256) {
    const uint2 pr = pairs[j];
    const int b = (int)pr.y / BSZ;
    slab[(size_t)b * CAP + gbase[b] + (j - bstart[b])] = pr;
  }
}

// -------------------------------------------- bucketed edge sort, pass B
// one block per bucket: LDS cursors over 500 nodes, scatter into 32KB window
__global__ __launch_bounds__(512) void k_bucketB(
    const uint2* __restrict__ slab, const int* __restrict__ gcur,
    const int* __restrict__ cur, int* __restrict__ esort) {
  __shared__ int lcur[BSZ];
  const int b = blockIdx.x, t = threadIdx.x;
  const int n0 = b * BSZ;
  for (int j = t; j < BSZ; j += 512) lcur[j] = cur[n0 + j];
  __syncthreads();
  const int cnt = gcur[b];
  const uint2* sp = slab + (size_t)b * CAP;
  for (int j = t; j < cnt; j += 512) {
    const uint2 pr = sp[j];
    const int p = atomicAdd(&lcur[(int)pr.y - n0], 1);
    esort[p] = (int)pr.x;
  }
}

// ---------------------------------------------------------------- aggregate 1
// one wave per node; lane covers 2 bf16 cols. int4 index loads, 8 gathers in flight.
__global__ __launch_bounds__(256) void k_agg1(
    unsigned short* __restrict__ ab, const int* __restrict__ esort,
    const int* __restrict__ cur, const float* __restrict__ inv) {
  const int i = (blockIdx.x * 256 + threadIdx.x) >> 6;
  const int lane = threadIdx.x & 63;
  if (i >= NN) return;
  int e = cur[i];
  const int end = cur[i + 1];
  float a0 = 0.f, b0 = 0.f, a1 = 0.f, b1 = 0.f;
  float a2 = 0.f, b2 = 0.f, a3 = 0.f, b3 = 0.f;
  const unsigned short* xb = ab + 128 + lane * 2;
  while (e < end && (e & 3)) {
    const unsigned v = *(const unsigned*)(xb + (size_t)esort[e] * 256);
    a0 += b2f((unsigned short)v); b0 += b2f((unsigned short)(v >> 16));
    ++e;
  }
  for (; e + 7 < end; e += 8) {
    const int4 s0 = *(const int4*)(esort + e);
    const int4 s1 = *(const int4*)(esort + e + 4);
    const unsigned v0 = *(const unsigned*)(xb + (size_t)s0.x * 256);
    const unsigned v1 = *(const unsigned*)(xb + (size_t)s0.y * 256);
    const unsigned v2 = *(const unsigned*)(xb + (size_t)s0.z * 256);
    const unsigned v3 = *(const unsigned*)(xb + (size_t)s0.w * 256);
    const unsigned v4 = *(const unsigned*)(xb + (size_t)s1.x * 256);
    const unsigned v5 = *(const unsigned*)(xb + (size_t)s1.y * 256);
    const unsigned v6 = *(const unsigned*)(xb + (size_t)s1.z * 256);
    const unsigned v7 = *(const unsigned*)(xb + (size_t)s1.w * 256);
    a0 += b2f((unsigned short)v0); b0 += b2f((unsigned short)(v0 >> 16));
    a1 += b2f((unsigned short)v1); b1 += b2f((unsigned short)(v1 >> 16));
    a2 += b2f((unsigned short)v2); b2 += b2f((unsigned short)(v2 >> 16));
    a3 += b2f((unsigned short)v3); b3 += b2f((unsigned short)(v3 >> 16));
    a0 += b2f((unsigned short)v4); b0 += b2f((unsigned short)(v4 >> 16));
    a1 += b2f((unsigned short)v5); b1 += b2f((unsigned short)(v5 >> 16));
    a2 += b2f((unsigned short)v6); b2 += b2f((unsigned short)(v6 >> 16));
    a3 += b2f((unsigned short)v7); b3 += b2f((unsigned short)(v7 >> 16));
  }
  if (e + 3 < end) {
    const int4 s0 = *(const int4*)(esort + e);
    const unsigned v0 = *(const unsigned*)(xb + (size_t)s0.x * 256);
    const unsigned v1 = *(const unsigned*)(xb + (size_t)s0.y * 256);
    const unsigned v2 = *(const unsigned*)(xb + (size_t)s0.z * 256);
    const unsigned v3 = *(const unsigned*)(xb + (size_t)s0.w * 256);
    a0 += b2f((unsigned short)v0); b0 += b2f((unsigned short)(v0 >> 16));
    a1 += b2f((unsigned short)v1); b1 += b2f((unsigned short)(v1 >> 16));
    a2 += b2f((unsigned short)v2); b2 += b2f((unsigned short)(v2 >> 16));
    a3 += b2f((unsigned short)v3); b3 += b2f((unsigned short)(v3 >> 16));
    e += 4;
  }
  for (; e < end; ++e) {
    const unsigned v = *(const unsigned*)(xb + (size_t)esort[e] * 256);
    a0 += b2f((unsigned short)v); b0 += b2f((unsigned short)(v >> 16));
  }
  const float sc = inv[i];
  const float sa = (a0 + a1) + (a2 + a3);
  const float sb = (b0 + b1) + (b2 + b3);
  const unsigned out =
      ((unsigned)f2b(sb * sc) << 16) | (unsigned)f2b(sa * sc);
  *(unsigned*)(ab + (size_t)i * 256 + lane * 2) = out;
}

// ---------------------------------------------------------------- GEMM 1 (MFMA)
__global__ __launch_bounds__(256) void k_gemm1(
    const unsigned short* __restrict__ ab, const unsigned short* __restrict__ wb,
    const float* __restrict__ b1l, unsigned short* __restrict__ hb) {
  __shared__ short sA[128 * 40];
  __shared__ short sB[128 * 40];
  const int tid = threadIdx.x;
  const int row0 = blockIdx.y * 128;
  const int col0 = blockIdx.x * 128;
  const int wave = tid >> 6, lane = tid & 63;
  const int quad = lane >> 4, m16 = lane & 15;
  const int wm = wave & 1, wn = wave >> 1;
  const int lr = tid >> 2;
  const int lk = (tid & 3) * 8;

  floatx4 acc[4][4];
#pragma unroll
  for (int a = 0; a < 4; ++a)
#pragma unroll
    for (int b = 0; b < 4; ++b) acc[a][b] = {0.f, 0.f, 0.f, 0.f};

  const int gr0 = row0 + lr, gr1 = row0 + lr + 64;
  const bool ok0 = gr0 < NN, ok1 = gr1 < NN;
  const unsigned short* aptr0 = ab + (size_t)gr0 * 256 + lk;
  const unsigned short* aptr1 = ab + (size_t)gr1 * 256 + lk;
  const unsigned short* bptr0 = wb + (size_t)(col0 + lr) * 256 + lk;
  const unsigned short* bptr1 = wb + (size_t)(col0 + lr + 64) * 256 + lk;
  short* sA0 = &sA[lr * 40 + lk];
  short* sA1 = &sA[(lr + 64) * 40 + lk];
  short* sB0 = &sB[lr * 40 + lk];
  short* sB1 = &sB[(lr + 64) * 40 + lk];
  const uint4 zz = make_uint4(0, 0, 0, 0);

  for (int kk = 0; kk < 256; kk += 32) {
    const uint4 av0 = ok0 ? *(const uint4*)(aptr0 + kk) : zz;
    const uint4 av1 = ok1 ? *(const uint4*)(aptr1 + kk) : zz;
    const uint4 bv0 = *(const uint4*)(bptr0 + kk);
    const uint4 bv1 = *(const uint4*)(bptr1 + kk);
    __syncthreads();
    *(uint4*)sA0 = av0;
    *(uint4*)sA1 = av1;
    *(uint4*)sB0 = bv0;
    *(uint4*)sB1 = bv1;
    __syncthreads();
    short8 af[4], bf[4];
#pragma unroll
    for (int mt = 0; mt < 4; ++mt)
      af[mt] = *(const short8*)&sA[(wm * 64 + mt * 16 + m16) * 40 + quad * 8];
#pragma unroll
    for (int nt = 0; nt < 4; ++nt)
      bf[nt] = *(const short8*)&sB[(wn * 64 + nt * 16 + m16) * 40 + quad * 8];
#pragma unroll
    for (int mt = 0; mt < 4; ++mt)
#pragma unroll
      for (int nt = 0; nt < 4; ++nt)
        acc[mt][nt] = __builtin_amdgcn_mfma_f32_16x16x32_bf16(
            af[mt], bf[nt], acc[mt][nt], 0, 0, 0);
  }

#pragma unroll
  for (int nt = 0; nt < 4; ++nt) {
    const int col = col0 + wn * 64 + nt * 16 + m16;
    const float bias = b1l[col];
#pragma unroll
    for (int mt = 0; mt < 4; ++mt) {
#pragma unroll
      for (int rg = 0; rg < 4; ++rg) {
        const int row = row0 + wm * 64 + mt * 16 + quad * 4 + rg;
        if (row < NN)
          hb[(size_t)row * 256 + col] = f2b(fmaxf(acc[mt][nt][rg] + bias, 0.f));
      }
    }
  }
}

// ---------------------------------------------------------------- layer-2 lin
__global__ __launch_bounds__(256) void k_lin2(
    const unsigned short* __restrict__ hb, const float* __restrict__ W2l,
    const float* __restrict__ W2r, float* __restrict__ t,
    float* __restrict__ r) {
  __shared__ float sW[2 * D2 * D1];
  for (int idx = threadIdx.x; idx < 2 * D2 * D1; idx += 256)
    sW[idx] = (idx < D2 * D1) ? W2l[idx] : W2r[idx - D2 * D1];
  __syncthreads();
  const int i = blockIdx.x * 256 + threadIdx.x;
  if (i >= NN) return;
  float accl[5] = {}, accr[5] = {};
  const unsigned short* hr = hb + (size_t)i * D1;
  for (int k = 0; k < D1; k += 8) {
    const uint4 hv = *(const uint4*)(hr + k);
    float hf[8];
    hf[0] = b2f((unsigned short)hv.x); hf[1] = b2f((unsigned short)(hv.x >> 16));
    hf[2] = b2f((unsigned short)hv.y); hf[3] = b2f((unsigned short)(hv.y >> 16));
    hf[4] = b2f((unsigned short)hv.z); hf[5] = b2f((unsigned short)(hv.z >> 16));
    hf[6] = b2f((unsigned short)hv.w); hf[7] = b2f((unsigned short)(hv.w >> 16));
#pragma unroll
    for (int n = 0; n < 5; ++n) {
      const float* wl = &sW[n * D1 + k];
      const float* wr = &sW[D2 * D1 + n * D1 + k];
#pragma unroll
      for (int j = 0; j < 8; ++j) {
        accl[n] += hf[j] * wl[j];
        accr[n] += hf[j] * wr[j];
      }
    }
  }
#pragma unroll
  for (int n = 0; n < 5; ++n) {
    t[(size_t)i * 8 + n] = accl[n];
    r[(size_t)i * D2 + n] = accr[n];
  }
}

// ---------------------------------------------------------------- layer-2 agg
__global__ __launch_bounds__(256) void k_layer2(
    const float* __restrict__ t, const float* __restrict__ r,
    const int* __restrict__ esort, const int* __restrict__ cur,
    const float* __restrict__ inv, const float* __restrict__ b2l,
    float* __restrict__ out) {
  const int i = blockIdx.x * blockDim.x + threadIdx.x;
  if (i >= NN) return;
  float A0 = 0, A1 = 0, A2 = 0, A3 = 0, A4 = 0;
  float B0 = 0, B1 = 0, B2 = 0, B3 = 0, B4 = 0;
  int e = cur[i];
  const int end = cur[i + 1];
  while (e < end && (e & 3)) {
    const float* tp = t + (size_t)esort[e] * 8;
    const float4 p = *(const float4*)tp;
    A0 += p.x; A1 += p.y; A2 += p.z; A3 += p.w; A4 += tp[4];
    ++e;
  }
  for (; e + 3 < end; e += 4) {
    const int4 s = *(const int4*)(esort + e);
    const float* t0 = t + (size_t)s.x * 8;
    const float* t1 = t + (size_t)s.y * 8;
    const float* t2 = t + (size_t)s.z * 8;
    const float* t3 = t + (size_t)s.w * 8;
    const float4 p0 = *(const float4*)t0; const float q0 = t0[4];
    const float4 p1 = *(const float4*)t1; const float q1 = t1[4];
    const float4 p2 = *(const float4*)t2; const float q2 = t2[4];
    const float4 p3 = *(const float4*)t3; const float q3 = t3[4];
    A0 += p0.x; A1 += p0.y; A2 += p0.z; A3 += p0.w; A4 += q0;
    B0 += p1.x; B1 += p1.y; B2 += p1.z; B3 += p1.w; B4 += q1;
    A0 += p2.x; A1 += p2.y; A2 += p2.z; A3 += p2.w; A4 += q2;
    B0 += p3.x; B1 += p3.y; B2 += p3.z; B3 += p3.w; B4 += q3;
  }
  for (; e < end; ++e) {
    const float* tp = t + (size_t)esort[e] * 8;
    const float4 p = *(const float4*)tp;
    A0 += p.x; A1 += p.y; A2 += p.z; A3 += p.w; A4 += tp[4];
  }
  const float sc = inv[i];
  const float* rp = r + (size_t)i * D2;
  out[(size_t)i * D2 + 0] = fmaxf((A0 + B0) * sc + b2l[0] + rp[0], 0.f);
  out[(size_t)i * D2 + 1] = fmaxf((A1 + B1) * sc + b2l[1] + rp[1], 0.f);
  out[(size_t)i * D2 + 2] = fmaxf((A2 + B2) * sc + b2l[2] + rp[2], 0.f);
  out[(size_t)i * D2 + 3] = fmaxf((A3 + B3) * sc + b2l[3] + rp[3], 0.f);
  out[(size_t)i * D2 + 4] = fmaxf((A4 + B4) * sc + b2l[4] + rp[4], 0.f);
}

extern "C" void kernel_launch(void* const* d_in, const int* in_sizes, int n_in,
                              void* d_out, int out_size, void* d_ws,
                              size_t ws_size, hipStream_t stream) {
  const float* x   = (const float*)d_in[0];
  const int*   ei  = (const int*)d_in[1];
  const int*   src = ei;
  const int*   dst = ei + NE;
  const float* W1l = (const float*)d_in[2];
  const float* b1l = (const float*)d_in[3];
  const float* W1r = (const float*)d_in[4];
  const float* W2l = (const float*)d_in[5];
  const float* b2l = (const float*)d_in[6];
  const float* W2r = (const float*)d_in[7];
  float* out = (float*)d_out;

  // workspace layout (4-byte units)
  int*   deg   = (int*)d_ws;                     // NN
  int*   gcur  = deg + NN;                       // 128 (bucket cursors)
  int*   cur   = gcur + 128;                     // NN+1 (start offsets + sentinel)
  int*   bsum  = cur + NN + 1;                   // 256
  int*   esort = bsum + 256;                     // NE
  float* inv   = (float*)(esort + NE);           // NN
  unsigned short* ab = (unsigned short*)(inv + NN);        // NN*256 bf16
  unsigned short* wb = ab + (size_t)NN * 256;              // 256*256 bf16
  unsigned short* hb = wb + (size_t)D1 * 256;              // NN*256 bf16
  uint2* slab = (uint2*)hb;  // alias: 100*12288*8B = 9.8MB, dead before gemm1
  float* t = (float*)(hb + (size_t)NN * 256);              // NN*8 (padded)
  float* r = t + (size_t)NN * 8;                           // NN*5

  hipMemsetAsync(deg, 0, (size_t)(NN + 128) * sizeof(int), stream);  // deg+gcur

  k_prep<<<HB + XB + WB, 256, 0, stream>>>(dst, deg, x, ab, W1l, W1r, wb);
  k_scanA<<<NB, 256, 0, stream>>>(deg, cur, bsum);
  k_scanB<<<NB, 256, 0, stream>>>(deg, bsum, cur, inv);
  k_bucketA<<<CB, 256, 0, stream>>>(src, dst, gcur, slab);
  k_bucketB<<<NBUK, 512, 0, stream>>>(slab, gcur, cur, esort);
  k_agg1<<<(NN * 64 + 255) / 256, 256, 0, stream>>>(ab, esort, cur, inv);
  dim3 g1(2, (NN + 127) / 128);
  k_gemm1<<<g1, 256, 0, stream>>>(ab, wb, b1l, hb);
  k_lin2<<<(NN + 255) / 256, 256, 0, stream>>>(hb, W2l, W2r, t, r);
  k_layer2<<<(NN + 255) / 256, 256, 0, stream>>>(t, r, esort, cur, inv, b2l, out);
}

// Round 8
// 231.708 us; speedup vs baseline: 1.2028x; 1.1545x over previous
//
#include <hip/hip_runtime.h>

static constexpr int NN = 50000;   // nodes
static constexpr int NE = 800000;  // edges
static constexpr int D0 = 128;     // in dim
static constexpr int D1 = 256;     // hidden
static constexpr int D2 = 5;       // out

// fused prep grid partition (cvtx | cvtw)
static constexpr int XB = (NN * 32 + 255) / 256;   // 6250 cvtx blocks
static constexpr int WB = (D1 * 64) / 256;         // 64 cvtw blocks

// bucketed edge sort: BSZ pow2 so bucket = dst>>9
static constexpr int BSZ   = 512;                  // nodes per bucket
static constexpr int NBUK  = (NN + BSZ - 1) / BSZ; // 98
static constexpr int CAP   = 9216;   // slab cap (mean 8192, fixed seed, +11 sigma)
static constexpr int CB    = 400;    // chunk blocks in pass A
static constexpr int CHUNK = 2000;   // edges per chunk (CB*CHUNK == NE)

using short8  = __attribute__((ext_vector_type(8))) short;
using floatx4 = __attribute__((ext_vector_type(4))) float;

__device__ __forceinline__ unsigned short f2b(float f) {
  union { float f; unsigned u; } v; v.f = f;
  unsigned r = v.u + 0x7fffu + ((v.u >> 16) & 1u);  // RNE
  return (unsigned short)(r >> 16);
}
__device__ __forceinline__ float b2f(unsigned short s) {
  union { unsigned u; float f; } v; v.u = ((unsigned)s) << 16;
  return v.f;
}

// ------------------------------------------------- prep: cvtx | cvtw (no atomics)
__global__ __launch_bounds__(256) void k_prep(
    const float* __restrict__ x, unsigned short* __restrict__ ab,
    const float* __restrict__ W1l, const float* __restrict__ W1r,
    unsigned short* __restrict__ wb) {
  const int b = blockIdx.x, t = threadIdx.x;
  if (b < XB) {  // x -> bf16 into ab cols 128..255
    int idx = b * 256 + t;
    if (idx < NN * 32) {
      int node = idx >> 5, cg = idx & 31;
      float4 v = *(const float4*)(x + (size_t)node * D0 + cg * 4);
      ushort4 o;
      o.x = f2b(v.x); o.y = f2b(v.y); o.z = f2b(v.z); o.w = f2b(v.w);
      *(ushort4*)(ab + (size_t)node * 256 + 128 + cg * 4) = o;
    }
  } else {  // [W1l|W1r] -> bf16 wb[col][256]
    int idx = (b - XB) * 256 + t;
    int c = idx >> 6, k = (idx & 63) * 4;
    const float* srcp = (k < 128) ? (W1l + (size_t)c * 128 + k)
                                  : (W1r + (size_t)c * 128 + (k - 128));
    float4 v = *(const float4*)srcp;
    ushort4 o;
    o.x = f2b(v.x); o.y = f2b(v.y); o.z = f2b(v.z); o.w = f2b(v.w);
    *(ushort4*)(wb + (size_t)c * 256 + k) = o;
  }
}

// -------------------------------------------- bucketed edge sort, pass A
// chunk -> LDS bucket-sort -> coalesced slab writes; gcur[b] accumulates counts
__global__ __launch_bounds__(256) void k_bucketA(
    const int* __restrict__ src, const int* __restrict__ dst,
    int* __restrict__ gcur, uint2* __restrict__ slab) {
  __shared__ int hist[128], bstart[128], gbase[128], hcur[128], sscan[128];
  __shared__ uint2 pairs[CHUNK];
  const int t = threadIdx.x;
  const int e0 = blockIdx.x * CHUNK;
  if (t < 128) hist[t] = 0;
  __syncthreads();
  for (int j = t; j < CHUNK; j += 256)
    atomicAdd(&hist[dst[e0 + j] >> 9], 1);
  __syncthreads();
  if (t < 128) sscan[t] = hist[t];
  __syncthreads();
  for (int dd = 1; dd < 128; dd <<= 1) {
    int u = (t >= dd && t < 128) ? sscan[t - dd] : 0;
    __syncthreads();
    if (t < 128) sscan[t] += u;
    __syncthreads();
  }
  if (t < 128) {
    bstart[t] = sscan[t] - hist[t];
    gbase[t] = (t < NBUK && hist[t] > 0) ? atomicAdd(&gcur[t], hist[t]) : 0;
    hcur[t] = 0;
  }
  __syncthreads();
  for (int j = t; j < CHUNK; j += 256) {
    const int s = src[e0 + j], d = dst[e0 + j];
    const int b = d >> 9;
    const int pos = bstart[b] + atomicAdd(&hcur[b], 1);
    pairs[pos] = make_uint2((unsigned)s, (unsigned)d);
  }
  __syncthreads();
  for (int j = t; j < CHUNK; j += 256) {
    const uint2 pr = pairs[j];
    const int b = (int)pr.y >> 9;
    slab[(size_t)b * CAP + gbase[b] + (j - bstart[b])] = pr;
  }
}

// -------------------------------------------- pass BC: per-bucket CSR + scatter
// one block per bucket: LDS hist(512) -> deg/inv/cur, LDS cursors -> esort.
// bbase from in-block scan of gcur[98]. No global atomics anywhere.
__global__ __launch_bounds__(512) void k_bucketBC(
    const uint2* __restrict__ slab, const int* __restrict__ gcur,
    int* __restrict__ cur, float* __restrict__ inv,
    int* __restrict__ esort) {
  __shared__ int cnt[BSZ], s[BSZ], lcur[BSZ], g[128];
  const int b = blockIdx.x, t = threadIdx.x;
  const int n0 = b << 9;
  cnt[t] = 0;
  if (t < 128) g[t] = (t < NBUK) ? gcur[t] : 0;
  __syncthreads();
  // inclusive scan of g[0..127]
  for (int dd = 1; dd < 128; dd <<= 1) {
    int u = (t >= dd && t < 128) ? g[t - dd] : 0;
    __syncthreads();
    if (t < 128) g[t] += u;
    __syncthreads();
  }
  const int bbase = (b == 0) ? 0 : g[b - 1];
  const int cntE = gcur[b];
  const uint2* sp = slab + (size_t)b * CAP;
  for (int j = t; j < cntE; j += 512)
    atomicAdd(&cnt[(int)sp[j].y - n0], 1);
  __syncthreads();
  s[t] = cnt[t];
  __syncthreads();
  for (int dd = 1; dd < BSZ; dd <<= 1) {
    int u = (t >= dd) ? s[t - dd] : 0;
    __syncthreads();
    s[t] += u;
    __syncthreads();
  }
  const int start = bbase + (s[t] - cnt[t]);
  const int node = n0 + t;
  if (node < NN) {
    cur[node] = start;
    inv[node] = 1.0f / (float)max(cnt[t], 1);
  }
  lcur[t] = start;
  if (b == NBUK - 1 && t == 0) cur[NN] = NE;
  __syncthreads();
  for (int j = t; j < cntE; j += 512) {
    const uint2 pr = sp[j];
    const int p = atomicAdd(&lcur[(int)pr.y - n0], 1);
    esort[p] = (int)pr.x;
  }
}

// ---------------------------------------------------------------- aggregate 1
// one wave per node; lane covers 2 bf16 cols. int4 index loads, 8 gathers in flight.
__global__ __launch_bounds__(256) void k_agg1(
    unsigned short* __restrict__ ab, const int* __restrict__ esort,
    const int* __restrict__ cur, const float* __restrict__ inv) {
  const int i = (blockIdx.x * 256 + threadIdx.x) >> 6;
  const int lane = threadIdx.x & 63;
  if (i >= NN) return;
  int e = cur[i];
  const int end = cur[i + 1];
  float a0 = 0.f, b0 = 0.f, a1 = 0.f, b1 = 0.f;
  float a2 = 0.f, b2 = 0.f, a3 = 0.f, b3 = 0.f;
  const unsigned short* xb = ab + 128 + lane * 2;
  while (e < end && (e & 3)) {
    const unsigned v = *(const unsigned*)(xb + (size_t)esort[e] * 256);
    a0 += b2f((unsigned short)v); b0 += b2f((unsigned short)(v >> 16));
    ++e;
  }
  for (; e + 7 < end; e += 8) {
    const int4 s0 = *(const int4*)(esort + e);
    const int4 s1 = *(const int4*)(esort + e + 4);
    const unsigned v0 = *(const unsigned*)(xb + (size_t)s0.x * 256);
    const unsigned v1 = *(const unsigned*)(xb + (size_t)s0.y * 256);
    const unsigned v2 = *(const unsigned*)(xb + (size_t)s0.z * 256);
    const unsigned v3 = *(const unsigned*)(xb + (size_t)s0.w * 256);
    const unsigned v4 = *(const unsigned*)(xb + (size_t)s1.x * 256);
    const unsigned v5 = *(const unsigned*)(xb + (size_t)s1.y * 256);
    const unsigned v6 = *(const unsigned*)(xb + (size_t)s1.z * 256);
    const unsigned v7 = *(const unsigned*)(xb + (size_t)s1.w * 256);
    a0 += b2f((unsigned short)v0); b0 += b2f((unsigned short)(v0 >> 16));
    a1 += b2f((unsigned short)v1); b1 += b2f((unsigned short)(v1 >> 16));
    a2 += b2f((unsigned short)v2); b2 += b2f((unsigned short)(v2 >> 16));
    a3 += b2f((unsigned short)v3); b3 += b2f((unsigned short)(v3 >> 16));
    a0 += b2f((unsigned short)v4); b0 += b2f((unsigned short)(v4 >> 16));
    a1 += b2f((unsigned short)v5); b1 += b2f((unsigned short)(v5 >> 16));
    a2 += b2f((unsigned short)v6); b2 += b2f((unsigned short)(v6 >> 16));
    a3 += b2f((unsigned short)v7); b3 += b2f((unsigned short)(v7 >> 16));
  }
  if (e + 3 < end) {
    const int4 s0 = *(const int4*)(esort + e);
    const unsigned v0 = *(const unsigned*)(xb + (size_t)s0.x * 256);
    const unsigned v1 = *(const unsigned*)(xb + (size_t)s0.y * 256);
    const unsigned v2 = *(const unsigned*)(xb + (size_t)s0.z * 256);
    const unsigned v3 = *(const unsigned*)(xb + (size_t)s0.w * 256);
    a0 += b2f((unsigned short)v0); b0 += b2f((unsigned short)(v0 >> 16));
    a1 += b2f((unsigned short)v1); b1 += b2f((unsigned short)(v1 >> 16));
    a2 += b2f((unsigned short)v2); b2 += b2f((unsigned short)(v2 >> 16));
    a3 += b2f((unsigned short)v3); b3 += b2f((unsigned short)(v3 >> 16));
    e += 4;
  }
  for (; e < end; ++e) {
    const unsigned v = *(const unsigned*)(xb + (size_t)esort[e] * 256);
    a0 += b2f((unsigned short)v); b0 += b2f((unsigned short)(v >> 16));
  }
  const float sc = inv[i];
  const float sa = (a0 + a1) + (a2 + a3);
  const float sb = (b0 + b1) + (b2 + b3);
  const unsigned out =
      ((unsigned)f2b(sb * sc) << 16) | (unsigned)f2b(sa * sc);
  *(unsigned*)(ab + (size_t)i * 256 + lane * 2) = out;
}

// ---------------------------------------------------------------- GEMM 1 (MFMA)
// 128x128 tile, BK=64 (32 MFMA between barriers), stride 72 (2-way-free banks)
__global__ __launch_bounds__(256) void k_gemm1(
    const unsigned short* __restrict__ ab, const unsigned short* __restrict__ wb,
    const float* __restrict__ b1l, unsigned short* __restrict__ hb) {
  __shared__ short sA[128 * 72];
  __shared__ short sB[128 * 72];
  const int tid = threadIdx.x;
  const int row0 = blockIdx.y * 128;
  const int col0 = blockIdx.x * 128;
  const int wave = tid >> 6, lane = tid & 63;
  const int quad = lane >> 4, m16 = lane & 15;
  const int wm = wave & 1, wn = wave >> 1;
  const int lr = tid >> 2;       // 0..63
  const int lk = (tid & 3) * 8;  // 0,8,16,24

  floatx4 acc[4][4];
#pragma unroll
  for (int a = 0; a < 4; ++a)
#pragma unroll
    for (int b = 0; b < 4; ++b) acc[a][b] = {0.f, 0.f, 0.f, 0.f};

  const int gr0 = row0 + lr, gr1 = row0 + lr + 64;
  const bool ok0 = gr0 < NN, ok1 = gr1 < NN;
  const unsigned short* aptr0 = ab + (size_t)gr0 * 256 + lk;
  const unsigned short* aptr1 = ab + (size_t)gr1 * 256 + lk;
  const unsigned short* bptr0 = wb + (size_t)(col0 + lr) * 256 + lk;
  const unsigned short* bptr1 = wb + (size_t)(col0 + lr + 64) * 256 + lk;
  short* sA0 = &sA[lr * 72 + lk];
  short* sA1 = &sA[(lr + 64) * 72 + lk];
  short* sB0 = &sB[lr * 72 + lk];
  short* sB1 = &sB[(lr + 64) * 72 + lk];
  const uint4 zz = make_uint4(0, 0, 0, 0);

  for (int kk = 0; kk < 256; kk += 64) {
    const uint4 a00 = ok0 ? *(const uint4*)(aptr0 + kk) : zz;
    const uint4 a01 = ok0 ? *(const uint4*)(aptr0 + kk + 32) : zz;
    const uint4 a10 = ok1 ? *(const uint4*)(aptr1 + kk) : zz;
    const uint4 a11 = ok1 ? *(const uint4*)(aptr1 + kk + 32) : zz;
    const uint4 b00 = *(const uint4*)(bptr0 + kk);
    const uint4 b01 = *(const uint4*)(bptr0 + kk + 32);
    const uint4 b10 = *(const uint4*)(bptr1 + kk);
    const uint4 b11 = *(const uint4*)(bptr1 + kk + 32);
    __syncthreads();
    *(uint4*)sA0 = a00;
    *(uint4*)(sA0 + 32) = a01;
    *(uint4*)sA1 = a10;
    *(uint4*)(sA1 + 32) = a11;
    *(uint4*)sB0 = b00;
    *(uint4*)(sB0 + 32) = b01;
    *(uint4*)sB1 = b10;
    *(uint4*)(sB1 + 32) = b11;
    __syncthreads();
#pragma unroll
    for (int ko = 0; ko < 64; ko += 32) {
      short8 af[4], bf[4];
#pragma unroll
      for (int mt = 0; mt < 4; ++mt)
        af[mt] =
            *(const short8*)&sA[(wm * 64 + mt * 16 + m16) * 72 + ko + quad * 8];
#pragma unroll
      for (int nt = 0; nt < 4; ++nt)
        bf[nt] =
            *(const short8*)&sB[(wn * 64 + nt * 16 + m16) * 72 + ko + quad * 8];
#pragma unroll
      for (int mt = 0; mt < 4; ++mt)
#pragma unroll
        for (int nt = 0; nt < 4; ++nt)
          acc[mt][nt] = __builtin_amdgcn_mfma_f32_16x16x32_bf16(
              af[mt], bf[nt], acc[mt][nt], 0, 0, 0);
    }
  }

#pragma unroll
  for (int nt = 0; nt < 4; ++nt) {
    const int col = col0 + wn * 64 + nt * 16 + m16;
    const float bias = b1l[col];
#pragma unroll
    for (int mt = 0; mt < 4; ++mt) {
#pragma unroll
      for (int rg = 0; rg < 4; ++rg) {
        const int row = row0 + wm * 64 + mt * 16 + quad * 4 + rg;
        if (row < NN)
          hb[(size_t)row * 256 + col] = f2b(fmaxf(acc[mt][nt][rg] + bias, 0.f));
      }
    }
  }
}

// ---------------------------------------------------------------- layer-2 lin
__global__ __launch_bounds__(256) void k_lin2(
    const unsigned short* __restrict__ hb, const float* __restrict__ W2l,
    const float* __restrict__ W2r, float* __restrict__ t,
    float* __restrict__ r) {
  __shared__ float sW[2 * D2 * D1];
  for (int idx = threadIdx.x; idx < 2 * D2 * D1; idx += 256)
    sW[idx] = (idx < D2 * D1) ? W2l[idx] : W2r[idx - D2 * D1];
  __syncthreads();
  const int i = blockIdx.x * 256 + threadIdx.x;
  if (i >= NN) return;
  float accl[5] = {}, accr[5] = {};
  const unsigned short* hr = hb + (size_t)i * D1;
  for (int k = 0; k < D1; k += 8) {
    const uint4 hv = *(const uint4*)(hr + k);
    float hf[8];
    hf[0] = b2f((unsigned short)hv.x); hf[1] = b2f((unsigned short)(hv.x >> 16));
    hf[2] = b2f((unsigned short)hv.y); hf[3] = b2f((unsigned short)(hv.y >> 16));
    hf[4] = b2f((unsigned short)hv.z); hf[5] = b2f((unsigned short)(hv.z >> 16));
    hf[6] = b2f((unsigned short)hv.w); hf[7] = b2f((unsigned short)(hv.w >> 16));
#pragma unroll
    for (int n = 0; n < 5; ++n) {
      const float* wl = &sW[n * D1 + k];
      const float* wr = &sW[D2 * D1 + n * D1 + k];
#pragma unroll
      for (int j = 0; j < 8; ++j) {
        accl[n] += hf[j] * wl[j];
        accr[n] += hf[j] * wr[j];
      }
    }
  }
#pragma unroll
  for (int n = 0; n < 5; ++n) {
    t[(size_t)i * 8 + n] = accl[n];
    r[(size_t)i * D2 + n] = accr[n];
  }
}

// ---------------------------------------------------------------- layer-2 agg
__global__ __launch_bounds__(256) void k_layer2(
    const float* __restrict__ t, const float* __restrict__ r,
    const int* __restrict__ esort, const int* __restrict__ cur,
    const float* __restrict__ inv, const float* __restrict__ b2l,
    float* __restrict__ out) {
  const int i = blockIdx.x * blockDim.x + threadIdx.x;
  if (i >= NN) return;
  float A0 = 0, A1 = 0, A2 = 0, A3 = 0, A4 = 0;
  float B0 = 0, B1 = 0, B2 = 0, B3 = 0, B4 = 0;
  int e = cur[i];
  const int end = cur[i + 1];
  while (e < end && (e & 3)) {
    const float* tp = t + (size_t)esort[e] * 8;
    const float4 p = *(const float4*)tp;
    A0 += p.x; A1 += p.y; A2 += p.z; A3 += p.w; A4 += tp[4];
    ++e;
  }
  for (; e + 3 < end; e += 4) {
    const int4 s = *(const int4*)(esort + e);
    const float* t0 = t + (size_t)s.x * 8;
    const float* t1 = t + (size_t)s.y * 8;
    const float* t2 = t + (size_t)s.z * 8;
    const float* t3 = t + (size_t)s.w * 8;
    const float4 p0 = *(const float4*)t0; const float q0 = t0[4];
    const float4 p1 = *(const float4*)t1; const float q1 = t1[4];
    const float4 p2 = *(const float4*)t2; const float q2 = t2[4];
    const float4 p3 = *(const float4*)t3; const float q3 = t3[4];
    A0 += p0.x; A1 += p0.y; A2 += p0.z; A3 += p0.w; A4 += q0;
    B0 += p1.x; B1 += p1.y; B2 += p1.z; B3 += p1.w; B4 += q1;
    A0 += p2.x; A1 += p2.y; A2 += p2.z; A3 += p2.w; A4 += q2;
    B0 += p3.x; B1 += p3.y; B2 += p3.z; B3 += p3.w; B4 += q3;
  }
  for (; e < end; ++e) {
    const float* tp = t + (size_t)esort[e] * 8;
    const float4 p = *(const float4*)tp;
    A0 += p.x; A1 += p.y; A2 += p.z; A3 += p.w; A4 += tp[4];
  }
  const float sc = inv[i];
  const float* rp = r + (size_t)i * D2;
  out[(size_t)i * D2 + 0] = fmaxf((A0 + B0) * sc + b2l[0] + rp[0], 0.f);
  out[(size_t)i * D2 + 1] = fmaxf((A1 + B1) * sc + b2l[1] + rp[1], 0.f);
  out[(size_t)i * D2 + 2] = fmaxf((A2 + B2) * sc + b2l[2] + rp[2], 0.f);
  out[(size_t)i * D2 + 3] = fmaxf((A3 + B3) * sc + b2l[3] + rp[3], 0.f);
  out[(size_t)i * D2 + 4] = fmaxf((A4 + B4) * sc + b2l[4] + rp[4], 0.f);
}

extern "C" void kernel_launch(void* const* d_in, const int* in_sizes, int n_in,
                              void* d_out, int out_size, void* d_ws,
                              size_t ws_size, hipStream_t stream) {
  const float* x   = (const float*)d_in[0];
  const int*   ei  = (const int*)d_in[1];
  const int*   src = ei;
  const int*   dst = ei + NE;
  const float* W1l = (const float*)d_in[2];
  const float* b1l = (const float*)d_in[3];
  const float* W1r = (const float*)d_in[4];
  const float* W2l = (const float*)d_in[5];
  const float* b2l = (const float*)d_in[6];
  const float* W2r = (const float*)d_in[7];
  float* out = (float*)d_out;

  // workspace layout (4-byte units)
  int*   gcur  = (int*)d_ws;                     // 128 (bucket counts)
  int*   cur   = gcur + 128;                     // NN+1 (start offsets + sentinel)
  int*   esort = cur + NN + 1;                   // NE
  float* inv   = (float*)(esort + NE);           // NN
  unsigned short* ab = (unsigned short*)(inv + NN);        // NN*256 bf16
  unsigned short* wb = ab + (size_t)NN * 256;              // 256*256 bf16
  unsigned short* hb = wb + (size_t)D1 * 256;              // NN*256 bf16
  uint2* slab = (uint2*)hb;  // alias: 98*9216*8B = 7.2MB, dead before gemm1
  float* t = (float*)(hb + (size_t)NN * 256);              // NN*8 (padded)
  float* r = t + (size_t)NN * 8;                           // NN*5

  hipMemsetAsync(gcur, 0, 128 * sizeof(int), stream);

  k_prep<<<XB + WB, 256, 0, stream>>>(x, ab, W1l, W1r, wb);
  k_bucketA<<<CB, 256, 0, stream>>>(src, dst, gcur, slab);
  k_bucketBC<<<NBUK, 512, 0, stream>>>(slab, gcur, cur, inv, esort);
  k_agg1<<<(NN * 64 + 255) / 256, 256, 0, stream>>>(ab, esort, cur, inv);
  dim3 g1(2, (NN + 127) / 128);
  k_gemm1<<<g1, 256, 0, stream>>>(ab, wb, b1l, hb);
  k_lin2<<<(NN + 255) / 256, 256, 0, stream>>>(hb, W2l, W2r, t, r);
  k_layer2<<<(NN + 255) / 256, 256, 0, stream>>>(t, r, esort, cur, inv, b2l, out);
}

// Round 9
// 182.839 us; speedup vs baseline: 1.5243x; 1.2673x over previous
//
#include <hip/hip_runtime.h>

static constexpr int NN = 50000;   // nodes
static constexpr int NE = 800000;  // edges
static constexpr int D0 = 128;     // in dim
static constexpr int D1 = 256;     // hidden
static constexpr int D2 = 5;       // out

// fused prepA grid partition (cvtx | cvtw1 | cvtw2 | bucketA)
static constexpr int XB = (NN * 32 + 255) / 256;   // 6250 cvtx blocks
static constexpr int WB = (D1 * 64) / 256;         // 64 cvtw blocks
static constexpr int PB = 4;                       // w2b convert blocks

// bucketed edge sort: BSZ pow2 so bucket = dst>>9
static constexpr int BSZ   = 512;                  // nodes per bucket
static constexpr int NBUK  = (NN + BSZ - 1) / BSZ; // 98
static constexpr int CAP   = 9216;   // slab cap (mean 8192, +11 sigma)
static constexpr int CB    = 400;    // chunk blocks in pass A
static constexpr int CHUNK = 2000;   // edges per chunk (CB*CHUNK == NE)

using short8  = __attribute__((ext_vector_type(8))) short;
using floatx4 = __attribute__((ext_vector_type(4))) float;

__device__ __forceinline__ unsigned short f2b(float f) {
  union { float f; unsigned u; } v; v.f = f;
  unsigned r = v.u + 0x7fffu + ((v.u >> 16) & 1u);  // RNE
  return (unsigned short)(r >> 16);
}
__device__ __forceinline__ float b2f(unsigned short s) {
  union { unsigned u; float f; } v; v.u = ((unsigned)s) << 16;
  return v.f;
}

// ---------------------- fused prep (cvtx|cvtw1|cvtw2) + bucketA, one dispatch
__global__ __launch_bounds__(256) void k_prepA(
    const float* __restrict__ x, unsigned short* __restrict__ ab,
    const float* __restrict__ W1l, const float* __restrict__ W1r,
    unsigned short* __restrict__ wb, const float* __restrict__ W2l,
    const float* __restrict__ W2r, unsigned short* __restrict__ w2b,
    const int* __restrict__ src, const int* __restrict__ dst,
    int* __restrict__ gcur, uint2* __restrict__ slab) {
  __shared__ int hist[128], bstart[128], gbase[128], hcur[128], sscan[128];
  __shared__ uint2 pairs[CHUNK];
  const int b = blockIdx.x, t = threadIdx.x;
  if (b < XB) {  // x -> bf16 into ab cols 128..255
    int idx = b * 256 + t;
    if (idx < NN * 32) {
      int node = idx >> 5, cg = idx & 31;
      float4 v = *(const float4*)(x + (size_t)node * D0 + cg * 4);
      ushort4 o;
      o.x = f2b(v.x); o.y = f2b(v.y); o.z = f2b(v.z); o.w = f2b(v.w);
      *(ushort4*)(ab + (size_t)node * 256 + 128 + cg * 4) = o;
    }
    return;
  }
  if (b < XB + WB) {  // [W1l|W1r] -> bf16 wb[col][256]
    int idx = (b - XB) * 256 + t;
    int c = idx >> 6, k = (idx & 63) * 4;
    const float* srcp = (k < 128) ? (W1l + (size_t)c * 128 + k)
                                  : (W1r + (size_t)c * 128 + (k - 128));
    float4 v = *(const float4*)srcp;
    ushort4 o;
    o.x = f2b(v.x); o.y = f2b(v.y); o.z = f2b(v.z); o.w = f2b(v.w);
    *(ushort4*)(wb + (size_t)c * 256 + k) = o;
    return;
  }
  if (b < XB + WB + PB) {  // W2l/W2r -> bf16 w2b[16][256], rows 10..15 = 0
    int idx = (b - XB - WB) * 256 + t;  // [0,1024)
    int n = idx >> 6, k = (idx & 63) * 4;
    float4 v = {0.f, 0.f, 0.f, 0.f};
    if (n < 5) v = *(const float4*)(W2l + (size_t)n * D1 + k);
    else if (n < 10) v = *(const float4*)(W2r + (size_t)(n - 5) * D1 + k);
    ushort4 o;
    o.x = f2b(v.x); o.y = f2b(v.y); o.z = f2b(v.z); o.w = f2b(v.w);
    *(ushort4*)(w2b + (size_t)n * 256 + k) = o;
    return;
  }
  // ---- bucketA: chunk -> LDS bucket-sort -> coalesced slab writes
  const int ba = b - (XB + WB + PB);
  const int e0 = ba * CHUNK;
  if (t < 128) hist[t] = 0;
  __syncthreads();
  for (int j = t; j < CHUNK; j += 256)
    atomicAdd(&hist[dst[e0 + j] >> 9], 1);
  __syncthreads();
  if (t < 128) sscan[t] = hist[t];
  __syncthreads();
  for (int dd = 1; dd < 128; dd <<= 1) {
    int u = (t >= dd && t < 128) ? sscan[t - dd] : 0;
    __syncthreads();
    if (t < 128) sscan[t] += u;
    __syncthreads();
  }
  if (t < 128) {
    bstart[t] = sscan[t] - hist[t];
    gbase[t] = (t < NBUK && hist[t] > 0) ? atomicAdd(&gcur[t], hist[t]) : 0;
    hcur[t] = 0;
  }
  __syncthreads();
  for (int j = t; j < CHUNK; j += 256) {
    const int s = src[e0 + j], d = dst[e0 + j];
    const int bk = d >> 9;
    const int pos = bstart[bk] + atomicAdd(&hcur[bk], 1);
    pairs[pos] = make_uint2((unsigned)s, (unsigned)d);
  }
  __syncthreads();
  for (int j = t; j < CHUNK; j += 256) {
    const uint2 pr = pairs[j];
    const int bk = (int)pr.y >> 9;
    slab[(size_t)bk * CAP + gbase[bk] + (j - bstart[bk])] = pr;
  }
}

// -------------------------------------------- pass BC: per-bucket CSR + scatter
__global__ __launch_bounds__(512) void k_bucketBC(
    const uint2* __restrict__ slab, const int* __restrict__ gcur,
    int* __restrict__ cur, float* __restrict__ inv,
    int* __restrict__ esort) {
  __shared__ int cnt[BSZ], s[BSZ], lcur[BSZ], g[128];
  const int b = blockIdx.x, t = threadIdx.x;
  const int n0 = b << 9;
  cnt[t] = 0;
  if (t < 128) g[t] = (t < NBUK) ? gcur[t] : 0;
  __syncthreads();
  for (int dd = 1; dd < 128; dd <<= 1) {
    int u = (t >= dd && t < 128) ? g[t - dd] : 0;
    __syncthreads();
    if (t < 128) g[t] += u;
    __syncthreads();
  }
  const int bbase = (b == 0) ? 0 : g[b - 1];
  const int cntE = gcur[b];
  const uint2* sp = slab + (size_t)b * CAP;
  for (int j = t; j < cntE; j += 512)
    atomicAdd(&cnt[(int)sp[j].y - n0], 1);
  __syncthreads();
  s[t] = cnt[t];
  __syncthreads();
  for (int dd = 1; dd < BSZ; dd <<= 1) {
    int u = (t >= dd) ? s[t - dd] : 0;
    __syncthreads();
    s[t] += u;
    __syncthreads();
  }
  const int start = bbase + (s[t] - cnt[t]);
  const int node = n0 + t;
  if (node < NN) {
    cur[node] = start;
    inv[node] = 1.0f / (float)max(cnt[t], 1);
  }
  lcur[t] = start;
  if (b == NBUK - 1 && t == 0) cur[NN] = NE;
  __syncthreads();
  for (int j = t; j < cntE; j += 512) {
    const uint2 pr = sp[j];
    const int p = atomicAdd(&lcur[(int)pr.y - n0], 1);
    esort[p] = (int)pr.x;
  }
}

// ---------------------------------------------------------------- aggregate 1
__global__ __launch_bounds__(256) void k_agg1(
    unsigned short* __restrict__ ab, const int* __restrict__ esort,
    const int* __restrict__ cur, const float* __restrict__ inv) {
  const int i = (blockIdx.x * 256 + threadIdx.x) >> 6;
  const int lane = threadIdx.x & 63;
  if (i >= NN) return;
  int e = cur[i];
  const int end = cur[i + 1];
  float a0 = 0.f, b0 = 0.f, a1 = 0.f, b1 = 0.f;
  float a2 = 0.f, b2 = 0.f, a3 = 0.f, b3 = 0.f;
  const unsigned short* xb = ab + 128 + lane * 2;
  while (e < end && (e & 3)) {
    const unsigned v = *(const unsigned*)(xb + (size_t)esort[e] * 256);
    a0 += b2f((unsigned short)v); b0 += b2f((unsigned short)(v >> 16));
    ++e;
  }
  for (; e + 7 < end; e += 8) {
    const int4 s0 = *(const int4*)(esort + e);
    const int4 s1 = *(const int4*)(esort + e + 4);
    const unsigned v0 = *(const unsigned*)(xb + (size_t)s0.x * 256);
    const unsigned v1 = *(const unsigned*)(xb + (size_t)s0.y * 256);
    const unsigned v2 = *(const unsigned*)(xb + (size_t)s0.z * 256);
    const unsigned v3 = *(const unsigned*)(xb + (size_t)s0.w * 256);
    const unsigned v4 = *(const unsigned*)(xb + (size_t)s1.x * 256);
    const unsigned v5 = *(const unsigned*)(xb + (size_t)s1.y * 256);
    const unsigned v6 = *(const unsigned*)(xb + (size_t)s1.z * 256);
    const unsigned v7 = *(const unsigned*)(xb + (size_t)s1.w * 256);
    a0 += b2f((unsigned short)v0); b0 += b2f((unsigned short)(v0 >> 16));
    a1 += b2f((unsigned short)v1); b1 += b2f((unsigned short)(v1 >> 16));
    a2 += b2f((unsigned short)v2); b2 += b2f((unsigned short)(v2 >> 16));
    a3 += b2f((unsigned short)v3); b3 += b2f((unsigned short)(v3 >> 16));
    a0 += b2f((unsigned short)v4); b0 += b2f((unsigned short)(v4 >> 16));
    a1 += b2f((unsigned short)v5); b1 += b2f((unsigned short)(v5 >> 16));
    a2 += b2f((unsigned short)v6); b2 += b2f((unsigned short)(v6 >> 16));
    a3 += b2f((unsigned short)v7); b3 += b2f((unsigned short)(v7 >> 16));
  }
  if (e + 3 < end) {
    const int4 s0 = *(const int4*)(esort + e);
    const unsigned v0 = *(const unsigned*)(xb + (size_t)s0.x * 256);
    const unsigned v1 = *(const unsigned*)(xb + (size_t)s0.y * 256);
    const unsigned v2 = *(const unsigned*)(xb + (size_t)s0.z * 256);
    const unsigned v3 = *(const unsigned*)(xb + (size_t)s0.w * 256);
    a0 += b2f((unsigned short)v0); b0 += b2f((unsigned short)(v0 >> 16));
    a1 += b2f((unsigned short)v1); b1 += b2f((unsigned short)(v1 >> 16));
    a2 += b2f((unsigned short)v2); b2 += b2f((unsigned short)(v2 >> 16));
    a3 += b2f((unsigned short)v3); b3 += b2f((unsigned short)(v3 >> 16));
    e += 4;
  }
  for (; e < end; ++e) {
    const unsigned v = *(const unsigned*)(xb + (size_t)esort[e] * 256);
    a0 += b2f((unsigned short)v); b0 += b2f((unsigned short)(v >> 16));
  }
  const float sc = inv[i];
  const float sa = (a0 + a1) + (a2 + a3);
  const float sb = (b0 + b1) + (b2 + b3);
  const unsigned out =
      ((unsigned)f2b(sb * sc) << 16) | (unsigned)f2b(sa * sc);
  *(unsigned*)(ab + (size_t)i * 256 + lane * 2) = out;
}

// ------------------------------------- GEMM 1 + fused layer-2 linear (MFMA)
// 128x128 tile, BK=64. Epilogue: h=relu(acc+bias) -> LDS bf16 (reusing sA/sB),
// then t/r_partial[128x10] = h @ w2b^T via 32 more MFMAs. No hb array.
__global__ __launch_bounds__(256) void k_gemm1f(
    const unsigned short* __restrict__ ab, const unsigned short* __restrict__ wb,
    const unsigned short* __restrict__ w2b, const float* __restrict__ b1l,
    float* __restrict__ tt, float* __restrict__ rp) {
  __shared__ short sAB[2 * 128 * 72];  // sA | sB, later reused as sH[128][136]
  short* sA = sAB;
  short* sB = sAB + 128 * 72;
  const int tid = threadIdx.x;
  const int row0 = blockIdx.y * 128;
  const int hf = blockIdx.x;       // col half
  const int col0 = hf * 128;
  const int wave = tid >> 6, lane = tid & 63;
  const int quad = lane >> 4, m16 = lane & 15;
  const int wm = wave & 1, wn = wave >> 1;
  const int lr = tid >> 2;
  const int lk = (tid & 3) * 8;

  floatx4 acc[4][4];
#pragma unroll
  for (int a = 0; a < 4; ++a)
#pragma unroll
    for (int b = 0; b < 4; ++b) acc[a][b] = {0.f, 0.f, 0.f, 0.f};

  const int gr0 = row0 + lr, gr1 = row0 + lr + 64;
  const bool ok0 = gr0 < NN, ok1 = gr1 < NN;
  const unsigned short* aptr0 = ab + (size_t)gr0 * 256 + lk;
  const unsigned short* aptr1 = ab + (size_t)gr1 * 256 + lk;
  const unsigned short* bptr0 = wb + (size_t)(col0 + lr) * 256 + lk;
  const unsigned short* bptr1 = wb + (size_t)(col0 + lr + 64) * 256 + lk;
  short* sA0 = &sA[lr * 72 + lk];
  short* sA1 = &sA[(lr + 64) * 72 + lk];
  short* sB0 = &sB[lr * 72 + lk];
  short* sB1 = &sB[(lr + 64) * 72 + lk];
  const uint4 zz = make_uint4(0, 0, 0, 0);

  for (int kk = 0; kk < 256; kk += 64) {
    const uint4 a00 = ok0 ? *(const uint4*)(aptr0 + kk) : zz;
    const uint4 a01 = ok0 ? *(const uint4*)(aptr0 + kk + 32) : zz;
    const uint4 a10 = ok1 ? *(const uint4*)(aptr1 + kk) : zz;
    const uint4 a11 = ok1 ? *(const uint4*)(aptr1 + kk + 32) : zz;
    const uint4 b00 = *(const uint4*)(bptr0 + kk);
    const uint4 b01 = *(const uint4*)(bptr0 + kk + 32);
    const uint4 b10 = *(const uint4*)(bptr1 + kk);
    const uint4 b11 = *(const uint4*)(bptr1 + kk + 32);
    __syncthreads();
    *(uint4*)sA0 = a00;
    *(uint4*)(sA0 + 32) = a01;
    *(uint4*)sA1 = a10;
    *(uint4*)(sA1 + 32) = a11;
    *(uint4*)sB0 = b00;
    *(uint4*)(sB0 + 32) = b01;
    *(uint4*)sB1 = b10;
    *(uint4*)(sB1 + 32) = b11;
    __syncthreads();
#pragma unroll
    for (int ko = 0; ko < 64; ko += 32) {
      short8 af[4], bf[4];
#pragma unroll
      for (int mt = 0; mt < 4; ++mt)
        af[mt] =
            *(const short8*)&sA[(wm * 64 + mt * 16 + m16) * 72 + ko + quad * 8];
#pragma unroll
      for (int nt = 0; nt < 4; ++nt)
        bf[nt] =
            *(const short8*)&sB[(wn * 64 + nt * 16 + m16) * 72 + ko + quad * 8];
#pragma unroll
      for (int mt = 0; mt < 4; ++mt)
#pragma unroll
        for (int nt = 0; nt < 4; ++nt)
          acc[mt][nt] = __builtin_amdgcn_mfma_f32_16x16x32_bf16(
              af[mt], bf[nt], acc[mt][nt], 0, 0, 0);
    }
  }

  // ---- epilogue: h=relu(acc+bias) -> sH bf16; then t/r = h @ w2b^T
  __syncthreads();  // K-loop ds_reads done; safe to overwrite
  short* sH = sAB;  // [128][136]
#pragma unroll
  for (int nt = 0; nt < 4; ++nt) {
    const int cl = wn * 64 + nt * 16 + m16;
    const float bias = b1l[col0 + cl];
#pragma unroll
    for (int mt = 0; mt < 4; ++mt)
#pragma unroll
      for (int rg = 0; rg < 4; ++rg) {
        const int rl = wm * 64 + mt * 16 + quad * 4 + rg;
        sH[rl * 136 + cl] = (short)f2b(fmaxf(acc[mt][nt][rg] + bias, 0.f));
      }
  }
  __syncthreads();
  floatx4 c2[2] = {{0.f, 0.f, 0.f, 0.f}, {0.f, 0.f, 0.f, 0.f}};
#pragma unroll
  for (int kb = 0; kb < 4; ++kb) {
    const short8 bf2 =
        *(const short8*)&w2b[m16 * 256 + col0 + kb * 32 + quad * 8];
#pragma unroll
    for (int i = 0; i < 2; ++i) {
      const int mrow = (wave * 2 + i) * 16 + m16;
      const short8 af2 = *(const short8*)&sH[mrow * 136 + kb * 32 + quad * 8];
      c2[i] = __builtin_amdgcn_mfma_f32_16x16x32_bf16(af2, bf2, c2[i], 0, 0, 0);
    }
  }
  // C layout: col(n)=m16, row=quad*4+rg. n<5 -> t partial, 5..9 -> r partial.
#pragma unroll
  for (int i = 0; i < 2; ++i) {
    const int rbase = row0 + (wave * 2 + i) * 16 + quad * 4;
#pragma unroll
    for (int rg = 0; rg < 4; ++rg) {
      const int row = rbase + rg;
      if (row < NN) {
        if (m16 < 5)
          tt[(size_t)row * 16 + hf * 8 + m16] = c2[i][rg];
        else if (m16 < 10)
          rp[(size_t)hf * ((size_t)NN * 8) + (size_t)row * 8 + (m16 - 5)] =
              c2[i][rg];
      }
    }
  }
}

// ------------------------------------- layer-2 aggregate: 16 lanes per node
__global__ __launch_bounds__(256) void k_layer2(
    const float* __restrict__ tt, const float* __restrict__ rp,
    const int* __restrict__ esort, const int* __restrict__ cur,
    const float* __restrict__ inv, const float* __restrict__ b2l,
    float* __restrict__ out) {
  const int node = blockIdx.x * 16 + (threadIdx.x >> 4);
  const int l = threadIdx.x & 15;
  if (node >= NN) return;
  const int beg = cur[node], end = cur[node + 1];
  float s0 = 0.f, s1 = 0.f, s2 = 0.f, s3 = 0.f, s4 = 0.f;
  for (int e = beg + l; e < end; e += 16) {
    const float* tp = tt + (size_t)esort[e] * 16;
    const float4 p0 = *(const float4*)tp;
    const float q0 = tp[4];
    const float4 p1 = *(const float4*)(tp + 8);
    const float q1 = tp[12];
    s0 += p0.x + p1.x;
    s1 += p0.y + p1.y;
    s2 += p0.z + p1.z;
    s3 += p0.w + p1.w;
    s4 += q0 + q1;
  }
#pragma unroll
  for (int m = 1; m < 16; m <<= 1) {
    s0 += __shfl_xor(s0, m, 64);
    s1 += __shfl_xor(s1, m, 64);
    s2 += __shfl_xor(s2, m, 64);
    s3 += __shfl_xor(s3, m, 64);
    s4 += __shfl_xor(s4, m, 64);
  }
  if (l == 0) {
    const float sc = inv[node];
    const float* r0 = rp + (size_t)node * 8;
    const float* r1 = rp + (size_t)NN * 8 + (size_t)node * 8;
    out[(size_t)node * D2 + 0] = fmaxf(s0 * sc + b2l[0] + r0[0] + r1[0], 0.f);
    out[(size_t)node * D2 + 1] = fmaxf(s1 * sc + b2l[1] + r0[1] + r1[1], 0.f);
    out[(size_t)node * D2 + 2] = fmaxf(s2 * sc + b2l[2] + r0[2] + r1[2], 0.f);
    out[(size_t)node * D2 + 3] = fmaxf(s3 * sc + b2l[3] + r0[3] + r1[3], 0.f);
    out[(size_t)node * D2 + 4] = fmaxf(s4 * sc + b2l[4] + r0[4] + r1[4], 0.f);
  }
}

extern "C" void kernel_launch(void* const* d_in, const int* in_sizes, int n_in,
                              void* d_out, int out_size, void* d_ws,
                              size_t ws_size, hipStream_t stream) {
  const float* x   = (const float*)d_in[0];
  const int*   ei  = (const int*)d_in[1];
  const int*   src = ei;
  const int*   dst = ei + NE;
  const float* W1l = (const float*)d_in[2];
  const float* b1l = (const float*)d_in[3];
  const float* W1r = (const float*)d_in[4];
  const float* W2l = (const float*)d_in[5];
  const float* b2l = (const float*)d_in[6];
  const float* W2r = (const float*)d_in[7];
  float* out = (float*)d_out;

  // workspace layout: big aligned arrays first (16B-aligned offsets)
  unsigned short* ab  = (unsigned short*)d_ws;          // NN*256 bf16
  unsigned short* wb  = ab + (size_t)NN * 256;          // 256*256 bf16
  unsigned short* w2b = wb + 256 * 256;                 // 16*256 bf16
  float* tt   = (float*)(w2b + 16 * 256);               // NN*16 (t interleaved)
  float* rp   = tt + (size_t)NN * 16;                   // 2 * NN*8 (r partials)
  uint2* slab = (uint2*)(rp + (size_t)NN * 16);         // NBUK*CAP pairs
  int*   gcur = (int*)(slab + (size_t)NBUK * CAP);      // 128
  int*   cur  = gcur + 128;                             // NN+1
  int*   esort = cur + NN + 1;                          // NE
  float* inv  = (float*)(esort + NE);                   // NN

  hipMemsetAsync(gcur, 0, 128 * sizeof(int), stream);

  k_prepA<<<XB + WB + PB + CB, 256, 0, stream>>>(x, ab, W1l, W1r, wb, W2l, W2r,
                                                 w2b, src, dst, gcur, slab);
  k_bucketBC<<<NBUK, 512, 0, stream>>>(slab, gcur, cur, inv, esort);
  k_agg1<<<(NN * 64 + 255) / 256, 256, 0, stream>>>(ab, esort, cur, inv);
  dim3 g1(2, (NN + 127) / 128);
  k_gemm1f<<<g1, 256, 0, stream>>>(ab, wb, w2b, b1l, tt, rp);
  k_layer2<<<(NN + 15) / 16, 256, 0, stream>>>(tt, rp, esort, cur, inv, b2l,
                                               out);
}